// Round 1
// baseline (370.826 us; speedup 1.0000x reference)
//
#include <hip/hip_runtime.h>

// ---------------------------------------------------------------------------
// DeformableConvBlock: B=4, Cin=64, Cout=128, H=W=128, 3x3, pad 1
// Stage 1: offset conv (64 -> 18 ch)          -> d_ws
// Stage 2: bilinear sample (V in LDS) + GEMM  -> d_out
// ---------------------------------------------------------------------------

// Kernel 1: offset conv. One thread per pixel, 18 accumulators.
// Weight index is wave-uniform -> compiler emits s_load (SGPR weights).
__global__ __launch_bounds__(256) void offs_conv(
    const float* __restrict__ x, const float* __restrict__ ow,
    const float* __restrict__ ob, float* __restrict__ offs) {
  int gid = blockIdx.x * 256 + threadIdx.x;   // b*16384 + h*128 + w
  int w = gid & 127;
  int h = (gid >> 7) & 127;
  int b = gid >> 14;
  float acc[18];
#pragma unroll
  for (int i = 0; i < 18; ++i) acc[i] = ob[i];
  const float* xb = x + ((long)b << 20);      // b*64*128*128
  for (int c = 0; c < 64; ++c) {
    const float* xc = xb + (c << 14);
    float xv[9];
#pragma unroll
    for (int ky = 0; ky < 3; ++ky) {
      int y = h + ky - 1;
      bool yok = ((unsigned)y < 128u);
#pragma unroll
      for (int kx = 0; kx < 3; ++kx) {
        int xx = w + kx - 1;
        xv[ky * 3 + kx] = (yok && (unsigned)xx < 128u) ? xc[(y << 7) + xx] : 0.f;
      }
    }
#pragma unroll
    for (int t = 0; t < 9; ++t) {
#pragma unroll
      for (int oc = 0; oc < 18; ++oc)
        acc[oc] = fmaf(xv[t], ow[oc * 576 + c * 9 + t], acc[oc]);
    }
  }
#pragma unroll
  for (int oc = 0; oc < 18; ++oc)
    offs[((b * 18 + oc) << 14) + (h << 7) + w] = acc[oc];
}

// Kernel 2: deformable sample + implicit GEMM.
// Block = 256 threads, one (b, h, 16-pixel row tile).
// Phase 1: V[ck=c*9+k][p] fp32 in LDS (36.8 KB).
// Phase 2: each thread computes 2 o x 4 p, K=576 dot via float4.
__global__ __launch_bounds__(256) void deform_gemm(
    const float* __restrict__ x, const float* __restrict__ offs,
    const float* __restrict__ mw, const float* __restrict__ mb,
    float* __restrict__ out) {
  __shared__ float v_lds[576 * 16];  // [ck][p]
  int blk = blockIdx.x;              // b*1024 + h*8 + wt
  int wt = blk & 7;
  int h  = (blk >> 3) & 127;
  int b  = blk >> 10;
  int w0 = wt << 4;
  int tid = threadIdx.x;

  // ---- Phase 1: bilinear sampling into LDS ----
  // 288 units = 16 p x 9 k x 2 c-halves (32 c each)
  for (int idx = tid; idx < 288; idx += 256) {
    int p  = idx & 15;
    int kc = idx >> 4;          // 0..17
    int k  = kc % 9;
    int ch = kc / 9;            // c half: 0 or 1
    int ky = k / 3, kx = k - ky * 3;
    int wp = w0 + p;
    int obase = ((b * 18 + 2 * k) << 14) + (h << 7) + wp;
    float dy = offs[obase];
    float dx = offs[obase + (1 << 14)];
    float py = (float)(h - 1 + ky) + dy;
    float px = (float)(wp - 1 + kx) + dx;
    float fy = floorf(py), fx = floorf(px);
    float wy = py - fy, wx = px - fx;
    int y0 = (int)fy, x0 = (int)fx;
    int y1 = y0 + 1, x1 = x0 + 1;
    bool vy0 = (unsigned)y0 < 128u, vy1 = (unsigned)y1 < 128u;
    bool vx0 = (unsigned)x0 < 128u, vx1 = (unsigned)x1 < 128u;
    // fold validity masks into bilinear weights (branchless c-loop)
    float w00 = (vy0 && vx0) ? (1.f - wy) * (1.f - wx) : 0.f;
    float w01 = (vy0 && vx1) ? (1.f - wy) * wx : 0.f;
    float w10 = (vy1 && vx0) ? wy * (1.f - wx) : 0.f;
    float w11 = (vy1 && vx1) ? wy * wx : 0.f;
    int y0c = min(max(y0, 0), 127), y1c = min(max(y1, 0), 127);
    int x0c = min(max(x0, 0), 127), x1c = min(max(x1, 0), 127);
    int o00 = (y0c << 7) + x0c, o01 = (y0c << 7) + x1c;
    int o10 = (y1c << 7) + x0c, o11 = (y1c << 7) + x1c;
    const float* xb = x + ((long)b << 20) + ((long)ch << 19);  // + ch*32*16384
    int vaddr = k * 16 + p;
    int cb = ch * 32;
    for (int c = 0; c < 32; ++c) {
      const float* xc = xb + (c << 14);
      float v = w00 * xc[o00] + w01 * xc[o01] + w10 * xc[o10] + w11 * xc[o11];
      v_lds[(cb + c) * 144 + vaddr] = v;   // (c*9+k)*16 + p
    }
  }
  __syncthreads();

  // ---- Phase 2: GEMM  out[o,p] = sum_ck W[o,ck] * V[ck,p] ----
  int po = tid & 3;            // p group
  int oo = tid >> 2;           // 0..63
  int p0 = po << 2;
  int o0 = oo << 1;            // 2 consecutive output channels
  float acc[2][4] = {{0.f, 0.f, 0.f, 0.f}, {0.f, 0.f, 0.f, 0.f}};
  const float* wrow = mw + o0 * 576;
#pragma unroll 2
  for (int c4 = 0; c4 < 144; ++c4) {
    float va[4][4];
#pragma unroll
    for (int m = 0; m < 4; ++m) {
      float4 t = *(const float4*)&v_lds[(c4 * 4 + m) * 16 + p0];
      va[m][0] = t.x; va[m][1] = t.y; va[m][2] = t.z; va[m][3] = t.w;
    }
#pragma unroll
    for (int i = 0; i < 2; ++i) {
      float4 wv = *(const float4*)(wrow + i * 576 + c4 * 4);
#pragma unroll
      for (int j = 0; j < 4; ++j) {
        acc[i][j] = fmaf(wv.x, va[0][j],
                    fmaf(wv.y, va[1][j],
                    fmaf(wv.z, va[2][j],
                    fmaf(wv.w, va[3][j], acc[i][j]))));
      }
    }
  }
#pragma unroll
  for (int i = 0; i < 2; ++i) {
    float bias = mb[o0 + i];
    float4 r;
    r.x = acc[i][0] + bias;
    r.y = acc[i][1] + bias;
    r.z = acc[i][2] + bias;
    r.w = acc[i][3] + bias;
    *(float4*)&out[((b * 128 + o0 + i) << 14) + (h << 7) + w0 + p0] = r;
  }
}

extern "C" void kernel_launch(void* const* d_in, const int* in_sizes, int n_in,
                              void* d_out, int out_size, void* d_ws, size_t ws_size,
                              hipStream_t stream) {
  const float* x  = (const float*)d_in[0];
  const float* ow = (const float*)d_in[1];
  const float* ob = (const float*)d_in[2];
  const float* mw = (const float*)d_in[3];
  const float* mb = (const float*)d_in[4];
  float* out  = (float*)d_out;
  float* offs = (float*)d_ws;   // 4*18*128*128 floats = 4.5 MB

  offs_conv<<<256, 256, 0, stream>>>(x, ow, ob, offs);
  deform_gemm<<<4096, 256, 0, stream>>>(x, offs, mw, mb, out);
}

// Round 2
// 192.075 us; speedup vs baseline: 1.9306x; 1.9306x over previous
//
#include <hip/hip_runtime.h>

typedef __attribute__((ext_vector_type(8))) short bf16x8;
typedef __attribute__((ext_vector_type(4))) float f32x4;

__device__ __forceinline__ unsigned short f2bf(float f) {
  unsigned u = __builtin_bit_cast(unsigned, f);
  u += 0x7fffu + ((u >> 16) & 1u);   // round-to-nearest-even
  return (unsigned short)(u >> 16);
}

// ---------------------------------------------------------------------------
// Kernel 0: repack main_w fp32 [o=128][c=64][k=9] -> bf16 Wt [k][o][c]
// ---------------------------------------------------------------------------
__global__ __launch_bounds__(256) void prep_w(const float* __restrict__ mw,
                                              unsigned short* __restrict__ wt) {
  int idx = blockIdx.x * 256 + threadIdx.x;   // k*8192 + o*64 + c  (73728 total)
  int c = idx & 63;
  int o = (idx >> 6) & 127;
  int k = idx >> 13;
  wt[idx] = f2bf(mw[o * 576 + c * 9 + k]);
}

// ---------------------------------------------------------------------------
// Kernel 1: offset conv 64->18. Block = 64 pixels x 4 c-chunks (16 ch each),
// LDS reduce. 1024 blocks -> 16 waves/CU.
// ---------------------------------------------------------------------------
__global__ __launch_bounds__(256) void offs_conv(
    const float* __restrict__ x, const float* __restrict__ ow,
    const float* __restrict__ ob, float* __restrict__ offs) {
  __shared__ float red[4 * 18 * 64];
  int t = threadIdx.x;
  int px = t & 63;
  int cc = __builtin_amdgcn_readfirstlane(t >> 6);  // wave-uniform c-chunk
  int gp = (blockIdx.x << 6) + px;    // b*16384 + h*128 + w
  int w = gp & 127;
  int h = (gp >> 7) & 127;
  int b = gp >> 14;
  float acc[18];
#pragma unroll
  for (int i = 0; i < 18; ++i) acc[i] = 0.f;
  const float* xc = x + ((long)b << 20) + ((long)cc << 18);  // + cc*16*16384
  const float* wb = ow + cc * 144;    // ow[oc][c][t9]: + oc*576 + ci*9 + t9
  for (int ci = 0; ci < 16; ++ci) {
    float xv[9];
#pragma unroll
    for (int ky = 0; ky < 3; ++ky) {
      int y = h + ky - 1;
      bool yok = ((unsigned)y < 128u);
#pragma unroll
      for (int kx = 0; kx < 3; ++kx) {
        int xx = w + kx - 1;
        xv[ky * 3 + kx] = (yok && (unsigned)xx < 128u) ? xc[(y << 7) + xx] : 0.f;
      }
    }
#pragma unroll
    for (int t9 = 0; t9 < 9; ++t9)
#pragma unroll
      for (int oc = 0; oc < 18; ++oc)
        acc[oc] = fmaf(xv[t9], wb[oc * 576 + ci * 9 + t9], acc[oc]);
    xc += 1 << 14;
  }
#pragma unroll
  for (int oc = 0; oc < 18; ++oc) red[(cc * 18 + oc) * 64 + px] = acc[oc];
  __syncthreads();
  for (int idx = t; idx < 1152; idx += 256) {
    int p2 = idx & 63;
    int oc = idx >> 6;
    int g2 = (blockIdx.x << 6) + p2;
    float s = red[oc * 64 + p2] + red[(18 + oc) * 64 + p2] +
              red[(36 + oc) * 64 + p2] + red[(54 + oc) * 64 + p2] + ob[oc];
    offs[(((g2 >> 14) * 18 + oc) << 14) + (g2 & 16383)] = s;
  }
}

// ---------------------------------------------------------------------------
// Kernel 2: deformable conv via MFMA.
// Block = 1 image row (128 px) x 128 out-channels, 4 waves.
// Loop k=0..8: sample V_k[p][c64] bf16 -> LDS [128][72], then
// 16x16x32 bf16 MFMA (A = Wt[k] from global/L2, B = V from LDS).
// ---------------------------------------------------------------------------
__global__ __launch_bounds__(256) void deform_mfma(
    const float* __restrict__ x, const float* __restrict__ offs,
    const unsigned short* __restrict__ wt, const float* __restrict__ mb,
    float* __restrict__ out) {
  __shared__ unsigned short vlds[128 * 72];
  int t = threadIdx.x;
  int P0 = blockIdx.x << 7;           // global pixel base (one full row)
  int b = P0 >> 14;
  int hw0 = P0 & 16383;
  int h = hw0 >> 7;

  // sampler identity: pixel-in-row + channel half
  int sp = t & 127;
  int ch = t >> 7;
  // mfma identity
  int lane = t & 63;
  int wv = t >> 6;                    // wave 0..3
  int wo = (wv >> 1) << 6;            // o base: 0 / 64
  int wp = (wv & 1) << 6;             // p base: 0 / 64
  int l15 = lane & 15;
  int l4k = (lane >> 4) << 3;         // k-element offset within fragment

  f32x4 acc[4][4];
#pragma unroll
  for (int m = 0; m < 4; ++m)
#pragma unroll
    for (int n = 0; n < 4; ++n) acc[m][n] = f32x4{0.f, 0.f, 0.f, 0.f};

  const float* xb = x + ((long)b << 20) + ((long)(ch << 5) << 14);
  unsigned short* vrow = &vlds[sp * 72 + (ch << 5)];
  const float* obase = offs + ((long)(b * 18) << 14) + hw0 + sp;

#pragma unroll 1
  for (int k = 0; k < 9; ++k) {
    // ---- sample V_k: this thread covers (pixel sp, channels ch*32..+32) ----
    int ky = k / 3, kx = k - ky * 3;
    float dy = obase[(2 * k) << 14];
    float dx = obase[(2 * k + 1) << 14];
    float py = (float)(h - 1 + ky) + dy;
    float pxf = (float)(sp - 1 + kx) + dx;
    float fy = floorf(py), fx = floorf(pxf);
    float wy = py - fy, wx = pxf - fx;
    int y0 = (int)fy, x0 = (int)fx;
    int y1 = y0 + 1, x1 = x0 + 1;
    bool vy0 = (unsigned)y0 < 128u, vy1 = (unsigned)y1 < 128u;
    bool vx0 = (unsigned)x0 < 128u, vx1 = (unsigned)x1 < 128u;
    float w00 = (vy0 && vx0) ? (1.f - wy) * (1.f - wx) : 0.f;
    float w01 = (vy0 && vx1) ? (1.f - wy) * wx : 0.f;
    float w10 = (vy1 && vx0) ? wy * (1.f - wx) : 0.f;
    float w11 = (vy1 && vx1) ? wy * wx : 0.f;
    int y0c = min(max(y0, 0), 127), y1c = min(max(y1, 0), 127);
    int x0c = min(max(x0, 0), 127), x1c = min(max(x1, 0), 127);
    int o00 = (y0c << 7) + x0c, o01 = (y0c << 7) + x1c;
    int o10 = (y1c << 7) + x0c, o11 = (y1c << 7) + x1c;
    const float* xc = xb;
#pragma unroll
    for (int q = 0; q < 8; ++q) {
      float v0 = w00 * xc[o00] + w01 * xc[o01] + w10 * xc[o10] + w11 * xc[o11];
      const float* xc1 = xc + (1 << 14);
      float v1 = w00 * xc1[o00] + w01 * xc1[o01] + w10 * xc1[o10] + w11 * xc1[o11];
      const float* xc2 = xc + (2 << 14);
      float v2 = w00 * xc2[o00] + w01 * xc2[o01] + w10 * xc2[o10] + w11 * xc2[o11];
      const float* xc3 = xc + (3 << 14);
      float v3 = w00 * xc3[o00] + w01 * xc3[o01] + w10 * xc3[o10] + w11 * xc3[o11];
      unsigned r01 = (unsigned)f2bf(v0) | ((unsigned)f2bf(v1) << 16);
      unsigned r23 = (unsigned)f2bf(v2) | ((unsigned)f2bf(v3) << 16);
      *(uint2*)(vrow + (q << 2)) = make_uint2(r01, r23);
      xc += 4 << 14;
    }
    __syncthreads();

    // ---- MFMA: acc[m][n] += Wt[k] x V_k ----
    const unsigned short* wk = wt + (((k << 7) + wo + l15) << 6) + l4k;
#pragma unroll
    for (int c0 = 0; c0 < 64; c0 += 32) {
      bf16x8 af[4], bfr[4];
#pragma unroll
      for (int m = 0; m < 4; ++m)
        af[m] = *(const bf16x8*)(wk + c0 + (m << 10));  // m*16 rows * 64 c
#pragma unroll
      for (int n = 0; n < 4; ++n)
        bfr[n] = *(const bf16x8*)&vlds[(wp + (n << 4) + l15) * 72 + c0 + l4k];
#pragma unroll
      for (int m = 0; m < 4; ++m)
#pragma unroll
        for (int n = 0; n < 4; ++n)
          acc[m][n] = __builtin_amdgcn_mfma_f32_16x16x32_bf16(
              af[m], bfr[n], acc[m][n], 0, 0, 0);
    }
    __syncthreads();   // protect vlds before next tap's writes
  }

  // ---- epilogue: D row = o (lane>>4)*4+reg, col = p (lane&15) ----
#pragma unroll
  for (int m = 0; m < 4; ++m) {
    int orow = wo + (m << 4) + ((lane >> 4) << 2);
#pragma unroll
    for (int r = 0; r < 4; ++r) {
      float bias = mb[orow + r];
      long ob2 = ((long)(b * 128 + orow + r) << 14) + hw0 + wp;
#pragma unroll
      for (int n = 0; n < 4; ++n)
        out[ob2 + (n << 4) + l15] = acc[m][n][r] + bias;
    }
  }
}

extern "C" void kernel_launch(void* const* d_in, const int* in_sizes, int n_in,
                              void* d_out, int out_size, void* d_ws, size_t ws_size,
                              hipStream_t stream) {
  const float* x  = (const float*)d_in[0];
  const float* ow = (const float*)d_in[1];
  const float* ob = (const float*)d_in[2];
  const float* mw = (const float*)d_in[3];
  const float* mb = (const float*)d_in[4];
  float* out  = (float*)d_out;
  float* offs = (float*)d_ws;                                   // 4.5 MB
  unsigned short* wt = (unsigned short*)((char*)d_ws + 4718592); // +147 KB

  prep_w<<<288, 256, 0, stream>>>(mw, wt);
  offs_conv<<<1024, 256, 0, stream>>>(x, ow, ob, offs);
  deform_mfma<<<512, 256, 0, stream>>>(x, offs, wt, mb, out);
}

// Round 3
// 103.100 us; speedup vs baseline: 3.5967x; 1.8630x over previous
//
#include <hip/hip_runtime.h>
#include <hip/hip_fp16.h>

typedef __attribute__((ext_vector_type(8))) short bf16x8;
typedef __attribute__((ext_vector_type(4))) float f32x4;

__device__ __forceinline__ unsigned short f2bf(float f) {
  unsigned u = __builtin_bit_cast(unsigned, f);
  u += 0x7fffu + ((u >> 16) & 1u);   // round-to-nearest-even
  return (unsigned short)(u >> 16);
}
__device__ __forceinline__ float bf2f(unsigned short s) {
  unsigned u = (unsigned)s << 16;
  return __builtin_bit_cast(float, u);
}
__device__ __forceinline__ unsigned short f2h(float f) {
  __half h = __float2half(f);
  return __builtin_bit_cast(unsigned short, h);
}
__device__ __forceinline__ float h2f(unsigned short bits) {
  __half h = __builtin_bit_cast(__half, bits);
  return __half2float(h);
}

// ---------------------------------------------------------------------------
// Kernel 0: repack main_w fp32 [o=128][c=64][k=9] -> bf16 Wt [k][o][c]
// ---------------------------------------------------------------------------
__global__ __launch_bounds__(256) void prep_w(const float* __restrict__ mw,
                                              unsigned short* __restrict__ wt) {
  int idx = blockIdx.x * 256 + threadIdx.x;
  int c = idx & 63;
  int o = (idx >> 6) & 127;
  int k = idx >> 13;
  wt[idx] = f2bf(mw[o * 576 + c * 9 + k]);
}

// ---------------------------------------------------------------------------
// Kernel 0b: transpose x NCHW fp32 -> NHWC bf16  xt[b][h][w][c]
// Block = one (b,h) row: 64c x 128w via padded LDS tile.
// ---------------------------------------------------------------------------
__global__ __launch_bounds__(256) void x_to_nhwc(const float* __restrict__ x,
                                                 unsigned short* __restrict__ xt) {
  __shared__ float tile[64 * 129];
  int bh = blockIdx.x;               // b*128 + h
  int t = threadIdx.x;
  const float* xrow = x + ((long)(bh >> 7) << 20) + ((bh & 127) << 7);
#pragma unroll
  for (int i = 0; i < 32; ++i) {
    int idx = t + (i << 8);          // c = idx>>7, w = idx&127
    tile[(idx >> 7) * 129 + (idx & 127)] = xrow[((long)(idx >> 7) << 14) + (idx & 127)];
  }
  __syncthreads();
  unsigned short* orow = xt + ((long)bh << 13);
#pragma unroll
  for (int i = 0; i < 32; ++i) {
    int idx = t + (i << 8);          // w = idx>>6, c = idx&63
    orow[idx] = f2bf(tile[(idx & 63) * 129 + (idx >> 6)]);
  }
}

// ---------------------------------------------------------------------------
// Kernel 1: offset conv 64->18 (fp32, unchanged from round 2)
// ---------------------------------------------------------------------------
__global__ __launch_bounds__(256) void offs_conv(
    const float* __restrict__ x, const float* __restrict__ ow,
    const float* __restrict__ ob, float* __restrict__ offs) {
  __shared__ float red[4 * 18 * 64];
  int t = threadIdx.x;
  int px = t & 63;
  int cc = __builtin_amdgcn_readfirstlane(t >> 6);
  int gp = (blockIdx.x << 6) + px;
  int w = gp & 127;
  int h = (gp >> 7) & 127;
  int b = gp >> 14;
  float acc[18];
#pragma unroll
  for (int i = 0; i < 18; ++i) acc[i] = 0.f;
  const float* xc = x + ((long)b << 20) + ((long)cc << 18);
  const float* wb = ow + cc * 144;
  for (int ci = 0; ci < 16; ++ci) {
    float xv[9];
#pragma unroll
    for (int ky = 0; ky < 3; ++ky) {
      int y = h + ky - 1;
      bool yok = ((unsigned)y < 128u);
#pragma unroll
      for (int kx = 0; kx < 3; ++kx) {
        int xx = w + kx - 1;
        xv[ky * 3 + kx] = (yok && (unsigned)xx < 128u) ? xc[(y << 7) + xx] : 0.f;
      }
    }
#pragma unroll
    for (int t9 = 0; t9 < 9; ++t9)
#pragma unroll
      for (int oc = 0; oc < 18; ++oc)
        acc[oc] = fmaf(xv[t9], wb[oc * 576 + ci * 9 + t9], acc[oc]);
    xc += 1 << 14;
  }
#pragma unroll
  for (int oc = 0; oc < 18; ++oc) red[(cc * 18 + oc) * 64 + px] = acc[oc];
  __syncthreads();
  for (int idx = t; idx < 1152; idx += 256) {
    int p2 = idx & 63;
    int oc = idx >> 6;
    int g2 = (blockIdx.x << 6) + p2;
    float s = red[oc * 64 + p2] + red[(18 + oc) * 64 + p2] +
              red[(36 + oc) * 64 + p2] + red[(54 + oc) * 64 + p2] + ob[oc];
    offs[(((g2 >> 14) * 18 + oc) << 14) + (g2 & 16383)] = s;
  }
}

// ---------------------------------------------------------------------------
// Kernel 2: deformable conv via MFMA, NHWC-bf16 gather.
// Block = 1 image row (128 px) x 128 out-ch, 4 waves, XCD-swizzled grid.
// Per block: build sampling table (9 taps x 128 px), then per tap:
//   sample V_k[px][c64] from xt (contiguous 128B corner lines) -> LDS,
//   MFMA 16x16x32 bf16 accumulate.
// ---------------------------------------------------------------------------
__global__ __launch_bounds__(256, 4) void deform_mfma(
    const unsigned short* __restrict__ xt, const float* __restrict__ offs,
    const unsigned short* __restrict__ wt, const float* __restrict__ mb,
    float* __restrict__ out) {
  __shared__ uint4 wtab[9][128];               // 18 KB: w00..w11 fp16, y0y1/x0x1 short
  __shared__ unsigned short vlds[128 * 72];    // 18 KB: V[px][c] bf16, pad 72

  int l = blockIdx.x;
  int bid = ((l & 7) << 6) + (l >> 3);         // XCD swizzle: 64 consec rows/XCD
  int b = bid >> 7;
  int h = bid & 127;
  int t = threadIdx.x;
  int lane = t & 63;
  int wv = t >> 6;
  int wo = (wv >> 1) << 6;
  int wp = (wv & 1) << 6;
  int l15 = lane & 15;
  int l4k = (lane >> 4) << 3;

  // ---- build sampling table: 1152 = 9 taps x 128 px ----
  const float* ob_ = offs + ((long)(b * 18) << 14) + (h << 7);
  for (int idx = t; idx < 1152; idx += 256) {
    int px = idx & 127, k = idx >> 7;
    int ky = k / 3, kx = k - 3 * ky;
    float dy = ob_[((2 * k) << 14) + px];
    float dx = ob_[((2 * k + 1) << 14) + px];
    float py = (float)(h - 1 + ky) + dy;
    float pxf = (float)(px - 1 + kx) + dx;
    float fy = floorf(py), fx = floorf(pxf);
    float wy = py - fy, wx = pxf - fx;
    int y0 = (int)fy, x0 = (int)fx;
    int y1 = y0 + 1, x1 = x0 + 1;
    bool vy0 = (unsigned)y0 < 128u, vy1 = (unsigned)y1 < 128u;
    bool vx0 = (unsigned)x0 < 128u, vx1 = (unsigned)x1 < 128u;
    float w00 = (vy0 && vx0) ? (1.f - wy) * (1.f - wx) : 0.f;
    float w01 = (vy0 && vx1) ? (1.f - wy) * wx : 0.f;
    float w10 = (vy1 && vx0) ? wy * (1.f - wx) : 0.f;
    float w11 = (vy1 && vx1) ? wy * wx : 0.f;
    int y0c = min(max(y0, 0), 127), y1c = min(max(y1, 0), 127);
    int x0c = min(max(x0, 0), 127), x1c = min(max(x1, 0), 127);
    wtab[k][px] = make_uint4(
        (unsigned)f2h(w00) | ((unsigned)f2h(w01) << 16),
        (unsigned)f2h(w10) | ((unsigned)f2h(w11) << 16),
        (unsigned)(unsigned short)y0c | ((unsigned)(unsigned short)y1c << 16),
        (unsigned)(unsigned short)x0c | ((unsigned)(unsigned short)x1c << 16));
  }

  f32x4 acc[4][4];
#pragma unroll
  for (int m = 0; m < 4; ++m)
#pragma unroll
    for (int n = 0; n < 4; ++n) acc[m][n] = f32x4{0.f, 0.f, 0.f, 0.f};

  const unsigned short* xb = xt + ((long)b << 20);
  __syncthreads();

#pragma unroll 1
  for (int k = 0; k < 9; ++k) {
    // ---- sample: 1024 units = 128 px x 8 c-chunks; 8 lanes share a px ----
#pragma unroll
    for (int it = 0; it < 4; ++it) {
      int idx2 = t + (it << 8);
      int px = idx2 >> 3, chunk = idx2 & 7;
      uint4 e = wtab[k][px];
      float w00 = h2f((unsigned short)(e.x & 0xffff));
      float w01 = h2f((unsigned short)(e.x >> 16));
      float w10 = h2f((unsigned short)(e.y & 0xffff));
      float w11 = h2f((unsigned short)(e.y >> 16));
      int y0 = (int)(short)(e.z & 0xffff), y1 = (int)(short)(e.z >> 16);
      int x0 = (int)(short)(e.w & 0xffff), x1 = (int)(short)(e.w >> 16);
      int co = chunk << 3;
      const unsigned short* r0 = xb + (y0 << 13) + co;
      const unsigned short* r1 = xb + (y1 << 13) + co;
      bf16x8 a00 = *(const bf16x8*)(r0 + (x0 << 6));
      bf16x8 a01 = *(const bf16x8*)(r0 + (x1 << 6));
      bf16x8 a10 = *(const bf16x8*)(r1 + (x0 << 6));
      bf16x8 a11 = *(const bf16x8*)(r1 + (x1 << 6));
      unsigned rr[4];
#pragma unroll
      for (int j = 0; j < 4; ++j) {
        float v0 = w00 * bf2f((unsigned short)a00[2 * j]) +
                   w01 * bf2f((unsigned short)a01[2 * j]) +
                   w10 * bf2f((unsigned short)a10[2 * j]) +
                   w11 * bf2f((unsigned short)a11[2 * j]);
        float v1 = w00 * bf2f((unsigned short)a00[2 * j + 1]) +
                   w01 * bf2f((unsigned short)a01[2 * j + 1]) +
                   w10 * bf2f((unsigned short)a10[2 * j + 1]) +
                   w11 * bf2f((unsigned short)a11[2 * j + 1]);
        rr[j] = (unsigned)f2bf(v0) | ((unsigned)f2bf(v1) << 16);
      }
      *(uint4*)&vlds[px * 72 + co] = make_uint4(rr[0], rr[1], rr[2], rr[3]);
    }
    __syncthreads();

    // ---- MFMA: acc[m][n] += Wt[k] x V_k ----
    const unsigned short* wk = wt + (((k << 7) + wo + l15) << 6) + l4k;
#pragma unroll
    for (int c0 = 0; c0 < 64; c0 += 32) {
      bf16x8 af[4], bfr[4];
#pragma unroll
      for (int m = 0; m < 4; ++m)
        af[m] = *(const bf16x8*)(wk + c0 + (m << 10));
#pragma unroll
      for (int n = 0; n < 4; ++n)
        bfr[n] = *(const bf16x8*)&vlds[(wp + (n << 4) + l15) * 72 + c0 + l4k];
#pragma unroll
      for (int m = 0; m < 4; ++m)
#pragma unroll
        for (int n = 0; n < 4; ++n)
          acc[m][n] = __builtin_amdgcn_mfma_f32_16x16x32_bf16(
              af[m], bfr[n], acc[m][n], 0, 0, 0);
    }
    __syncthreads();
  }

  // ---- epilogue: D row = o (lane>>4)*4+reg, col = p (lane&15) ----
  int hw0 = (h << 7);
#pragma unroll
  for (int m = 0; m < 4; ++m) {
    int orow = wo + (m << 4) + ((lane >> 4) << 2);
#pragma unroll
    for (int r = 0; r < 4; ++r) {
      float bias = mb[orow + r];
      long ob2 = ((long)(b * 128 + orow + r) << 14) + hw0 + wp;
#pragma unroll
      for (int n = 0; n < 4; ++n)
        out[ob2 + (n << 4) + l15] = acc[m][n][r] + bias;
    }
  }
}

extern "C" void kernel_launch(void* const* d_in, const int* in_sizes, int n_in,
                              void* d_out, int out_size, void* d_ws, size_t ws_size,
                              hipStream_t stream) {
  const float* x  = (const float*)d_in[0];
  const float* ow = (const float*)d_in[1];
  const float* ob = (const float*)d_in[2];
  const float* mw = (const float*)d_in[3];
  const float* mb = (const float*)d_in[4];
  float* out  = (float*)d_out;
  float* offs = (float*)d_ws;                                      // 4.5 MB
  unsigned short* wt = (unsigned short*)((char*)d_ws + 4718592);   // 147 KB
  unsigned short* xt = (unsigned short*)((char*)d_ws + 4866048);   // 8 MB

  prep_w<<<288, 256, 0, stream>>>(mw, wt);
  x_to_nhwc<<<512, 256, 0, stream>>>(x, xt);
  offs_conv<<<1024, 256, 0, stream>>>(x, ow, ob, offs);
  deform_mfma<<<512, 256, 0, stream>>>(xt, offs, wt, mb, out);
}

// Round 4
// 84.447 us; speedup vs baseline: 4.3912x; 1.2209x over previous
//
#include <hip/hip_runtime.h>
#include <hip/hip_fp16.h>

typedef __attribute__((ext_vector_type(8))) short bf16x8;
typedef __attribute__((ext_vector_type(4))) float f32x4;

__device__ __forceinline__ unsigned short f2bf(float f) {
  unsigned u = __builtin_bit_cast(unsigned, f);
  u += 0x7fffu + ((u >> 16) & 1u);   // round-to-nearest-even
  return (unsigned short)(u >> 16);
}
__device__ __forceinline__ float bf2f(unsigned short s) {
  unsigned u = (unsigned)s << 16;
  return __builtin_bit_cast(float, u);
}
__device__ __forceinline__ unsigned short f2h(float f) {
  __half h = __float2half(f);
  return __builtin_bit_cast(unsigned short, h);
}
__device__ __forceinline__ float h2f(unsigned short bits) {
  __half h = __builtin_bit_cast(__half, bits);
  return __half2float(h);
}

// ---------------------------------------------------------------------------
// Kernel 0: repack weights.
//   wt  [k][o=128][c=64] bf16  <- main_w fp32 [o][c][k]
//   wot [k][o=32 ][c=64] bf16  <- offset_w fp32 [18][c][k], zero-pad o>=18
// ---------------------------------------------------------------------------
__global__ __launch_bounds__(256) void prep_w(const float* __restrict__ mw,
                                              const float* __restrict__ ow,
                                              unsigned short* __restrict__ wt,
                                              unsigned short* __restrict__ wot) {
  int idx = blockIdx.x * 256 + threadIdx.x;
  if (idx < 73728) {
    int c = idx & 63;
    int o = (idx >> 6) & 127;
    int k = idx >> 13;
    wt[idx] = f2bf(mw[o * 576 + c * 9 + k]);
  } else if (idx < 73728 + 18432) {
    int i2 = idx - 73728;
    int c = i2 & 63;
    int o = (i2 >> 6) & 31;
    int k = i2 >> 11;
    wot[i2] = (o < 18) ? f2bf(ow[o * 576 + c * 9 + k]) : (unsigned short)0;
  }
}

// ---------------------------------------------------------------------------
// Kernel 0b: transpose x NCHW fp32 -> NHWC bf16  xt[b][h][w][c]
// ---------------------------------------------------------------------------
__global__ __launch_bounds__(256) void x_to_nhwc(const float* __restrict__ x,
                                                 unsigned short* __restrict__ xt) {
  __shared__ float tile[64 * 129];
  int bh = blockIdx.x;               // b*128 + h
  int t = threadIdx.x;
  const float* xrow = x + ((long)(bh >> 7) << 20) + ((bh & 127) << 7);
#pragma unroll
  for (int i = 0; i < 32; ++i) {
    int idx = t + (i << 8);          // c = idx>>7, w = idx&127
    tile[(idx >> 7) * 129 + (idx & 127)] = xrow[((long)(idx >> 7) << 14) + (idx & 127)];
  }
  __syncthreads();
  unsigned short* orow = xt + ((long)bh << 13);
#pragma unroll
  for (int i = 0; i < 32; ++i) {
    int idx = t + (i << 8);          // w = idx>>6, c = idx&63
    orow[idx] = f2bf(tile[(idx & 63) * 129 + (idx >> 6)]);
  }
}

// ---------------------------------------------------------------------------
// Kernel 1: offset conv 64->18 via MFMA. GEMM M=32(18 used) x K=576 x N=16384.
// Block = one (b,h) row, 4 waves x 32 px. B-frags straight from xt (global,
// L2-hot, clamp+mask for halo) -> no LDS, no barriers, high occupancy.
// ---------------------------------------------------------------------------
__global__ __launch_bounds__(256) void offs_mfma(
    const unsigned short* __restrict__ xt, const unsigned short* __restrict__ wot,
    const float* __restrict__ ob, float* __restrict__ offs) {
  int l = blockIdx.x;
  int bid = ((l & 7) << 6) + (l >> 3);   // XCD swizzle: 64 consecutive rows/XCD
  int h = bid & 127;
  int b = bid >> 7;
  int t = threadIdx.x;
  int lane = t & 63;
  int wv = t >> 6;
  int wp = wv << 5;                      // px base per wave
  int l15 = lane & 15;
  int l4k = (lane >> 4) << 3;

  f32x4 acc[2][2];
#pragma unroll
  for (int m = 0; m < 2; ++m)
#pragma unroll
    for (int n = 0; n < 2; ++n) acc[m][n] = f32x4{0.f, 0.f, 0.f, 0.f};

  const unsigned short* xb = xt + ((long)b << 20);

#pragma unroll 1
  for (int k = 0; k < 9; ++k) {
    int ky = k / 3, kx = k - 3 * ky;
    int y = h + ky - 1;
    bool yok = (unsigned)y < 128u;
    int yc = min(max(y, 0), 127);
    const unsigned short* xrow = xb + ((long)yc << 13);
    int pxo[2];
    bool pv[2];
#pragma unroll
    for (int n = 0; n < 2; ++n) {
      int px = wp + (n << 4) + l15 + kx - 1;
      pv[n] = yok && ((unsigned)px < 128u);
      pxo[n] = min(max(px, 0), 127) << 6;
    }
    const unsigned short* wk = wot + (((k << 5) + l15) << 6) + l4k;
#pragma unroll
    for (int c0 = 0; c0 < 64; c0 += 32) {
      bf16x8 af[2], bfr[2];
#pragma unroll
      for (int m = 0; m < 2; ++m)
        af[m] = *(const bf16x8*)(wk + c0 + (m << 10));   // +m*16*64
#pragma unroll
      for (int n = 0; n < 2; ++n) {
        bf16x8 v = *(const bf16x8*)(xrow + pxo[n] + c0 + l4k);
        if (!pv[n]) v = bf16x8{0, 0, 0, 0, 0, 0, 0, 0};
        bfr[n] = v;
      }
#pragma unroll
      for (int m = 0; m < 2; ++m)
#pragma unroll
        for (int n = 0; n < 2; ++n)
          acc[m][n] = __builtin_amdgcn_mfma_f32_16x16x32_bf16(
              af[m], bfr[n], acc[m][n], 0, 0, 0);
    }
  }

  int l4 = lane >> 4;
#pragma unroll
  for (int m = 0; m < 2; ++m) {
#pragma unroll
    for (int r = 0; r < 4; ++r) {
      int oc = (m << 4) + (l4 << 2) + r;
      if (oc < 18) {
        float bias = ob[oc];
#pragma unroll
        for (int n = 0; n < 2; ++n)
          offs[((long)(b * 18 + oc) << 14) + (h << 7) + wp + (n << 4) + l15] =
              acc[m][n][r] + bias;
      }
    }
  }
}

// ---------------------------------------------------------------------------
// Kernel 2: deformable conv via MFMA, NHWC-bf16 gather.
// Block = half row (64 px) x 128 out-ch, 4 waves, grid 1024, XCD-swizzled.
// Double-buffered V tile: sample tap k+1 while MFMA consumes tap k.
// LDS = 9.2K wtab + 2x9.2K vlds = 27.6 KB -> 5 blocks/CU.
// ---------------------------------------------------------------------------
__global__ __launch_bounds__(256) void deform_mfma(
    const unsigned short* __restrict__ xt, const float* __restrict__ offs,
    const unsigned short* __restrict__ wt, const float* __restrict__ mb,
    float* __restrict__ out) {
  __shared__ uint4 wtab[9][64];
  __shared__ unsigned short vlds[2][64 * 72];

  int l = blockIdx.x;
  int bid = ((l & 7) << 7) + (l >> 3);   // XCD swizzle: 128 consecutive bids/XCD
  int half = bid & 1;
  int h = (bid >> 1) & 127;
  int b = bid >> 8;
  int w0 = half << 6;
  int t = threadIdx.x;
  int lane = t & 63;
  int wv = t >> 6;
  int wo = (wv & 1) << 6;                // o base: 0 / 64 (4 m-frags)
  int wp = (wv >> 1) << 5;               // px base: 0 / 32 (2 n-frags)
  int l15 = lane & 15;
  int l4k = (lane >> 4) << 3;

  // ---- build sampling table: 576 = 9 taps x 64 px ----
  const float* ob_ = offs + ((long)(b * 18) << 14) + (h << 7) + w0;
  for (int idx = t; idx < 576; idx += 256) {
    int px = idx & 63, k = idx >> 6;
    int ky = k / 3, kx = k - 3 * ky;
    float dy = ob_[((2 * k) << 14) + px];
    float dx = ob_[((2 * k + 1) << 14) + px];
    float py = (float)(h - 1 + ky) + dy;
    float pxf = (float)(w0 + px - 1 + kx) + dx;
    float fy = floorf(py), fx = floorf(pxf);
    float wy = py - fy, wx = pxf - fx;
    int y0 = (int)fy, x0 = (int)fx;
    int y1 = y0 + 1, x1 = x0 + 1;
    bool vy0 = (unsigned)y0 < 128u, vy1 = (unsigned)y1 < 128u;
    bool vx0 = (unsigned)x0 < 128u, vx1 = (unsigned)x1 < 128u;
    float w00 = (vy0 && vx0) ? (1.f - wy) * (1.f - wx) : 0.f;
    float w01 = (vy0 && vx1) ? (1.f - wy) * wx : 0.f;
    float w10 = (vy1 && vx0) ? wy * (1.f - wx) : 0.f;
    float w11 = (vy1 && vx1) ? wy * wx : 0.f;
    int y0c = min(max(y0, 0), 127), y1c = min(max(y1, 0), 127);
    int x0c = min(max(x0, 0), 127), x1c = min(max(x1, 0), 127);
    wtab[k][px] = make_uint4(
        (unsigned)f2h(w00) | ((unsigned)f2h(w01) << 16),
        (unsigned)f2h(w10) | ((unsigned)f2h(w11) << 16),
        (unsigned)(unsigned short)y0c | ((unsigned)(unsigned short)y1c << 16),
        (unsigned)(unsigned short)x0c | ((unsigned)(unsigned short)x1c << 16));
  }

  f32x4 acc[4][2];
#pragma unroll
  for (int m = 0; m < 4; ++m)
#pragma unroll
    for (int n = 0; n < 2; ++n) acc[m][n] = f32x4{0.f, 0.f, 0.f, 0.f};

  const unsigned short* xb = xt + ((long)b << 20);

  // sample tap k into buf: 512 units = 64 px x 8 c-chunks, 2 iters/thread
  auto sample = [&](int k, unsigned short* buf) {
#pragma unroll
    for (int it = 0; it < 2; ++it) {
      int idx2 = t + (it << 8);
      int px = idx2 >> 3, chunk = idx2 & 7;
      uint4 e = wtab[k][px];
      float w00 = h2f((unsigned short)(e.x & 0xffff));
      float w01 = h2f((unsigned short)(e.x >> 16));
      float w10 = h2f((unsigned short)(e.y & 0xffff));
      float w11 = h2f((unsigned short)(e.y >> 16));
      int y0 = (int)(short)(e.z & 0xffff), y1 = (int)(short)(e.z >> 16);
      int x0 = (int)(short)(e.w & 0xffff), x1 = (int)(short)(e.w >> 16);
      int co = chunk << 3;
      const unsigned short* r0 = xb + (y0 << 13) + co;
      const unsigned short* r1 = xb + (y1 << 13) + co;
      bf16x8 a00 = *(const bf16x8*)(r0 + (x0 << 6));
      bf16x8 a01 = *(const bf16x8*)(r0 + (x1 << 6));
      bf16x8 a10 = *(const bf16x8*)(r1 + (x0 << 6));
      bf16x8 a11 = *(const bf16x8*)(r1 + (x1 << 6));
      unsigned rr[4];
#pragma unroll
      for (int j = 0; j < 4; ++j) {
        float v0 = w00 * bf2f((unsigned short)a00[2 * j]) +
                   w01 * bf2f((unsigned short)a01[2 * j]) +
                   w10 * bf2f((unsigned short)a10[2 * j]) +
                   w11 * bf2f((unsigned short)a11[2 * j]);
        float v1 = w00 * bf2f((unsigned short)a00[2 * j + 1]) +
                   w01 * bf2f((unsigned short)a01[2 * j + 1]) +
                   w10 * bf2f((unsigned short)a10[2 * j + 1]) +
                   w11 * bf2f((unsigned short)a11[2 * j + 1]);
        rr[j] = (unsigned)f2bf(v0) | ((unsigned)f2bf(v1) << 16);
      }
      *(uint4*)&buf[px * 72 + co] = make_uint4(rr[0], rr[1], rr[2], rr[3]);
    }
  };

  __syncthreads();          // wtab ready
  sample(0, vlds[0]);
  __syncthreads();          // buf0 ready

#pragma unroll 1
  for (int k = 0; k < 9; ++k) {
    const unsigned short* buf = vlds[k & 1];
    if (k < 8) sample(k + 1, vlds[(k + 1) & 1]);   // overlap with MFMA below

    const unsigned short* wk = wt + (((k << 7) + wo + l15) << 6) + l4k;
#pragma unroll
    for (int c0 = 0; c0 < 64; c0 += 32) {
      bf16x8 af[4], bfr[2];
#pragma unroll
      for (int m = 0; m < 4; ++m)
        af[m] = *(const bf16x8*)(wk + c0 + (m << 10));
#pragma unroll
      for (int n = 0; n < 2; ++n)
        bfr[n] = *(const bf16x8*)&buf[(wp + (n << 4) + l15) * 72 + c0 + l4k];
#pragma unroll
      for (int m = 0; m < 4; ++m)
#pragma unroll
        for (int n = 0; n < 2; ++n)
          acc[m][n] = __builtin_amdgcn_mfma_f32_16x16x32_bf16(
              af[m], bfr[n], acc[m][n], 0, 0, 0);
    }
    __syncthreads();        // next tap's buffer fully written & consumed
  }

  // ---- epilogue: D row = o (lane>>4)*4+reg, col = px (lane&15) ----
  int hw0 = (h << 7) + w0;
#pragma unroll
  for (int m = 0; m < 4; ++m) {
    int orow = wo + (m << 4) + ((lane >> 4) << 2);
#pragma unroll
    for (int r = 0; r < 4; ++r) {
      float bias = mb[orow + r];
      long ob2 = ((long)(b * 128 + orow + r) << 14) + hw0 + wp;
#pragma unroll
      for (int n = 0; n < 2; ++n)
        out[ob2 + (n << 4) + l15] = acc[m][n][r] + bias;
    }
  }
}

extern "C" void kernel_launch(void* const* d_in, const int* in_sizes, int n_in,
                              void* d_out, int out_size, void* d_ws, size_t ws_size,
                              hipStream_t stream) {
  const float* x  = (const float*)d_in[0];
  const float* ow = (const float*)d_in[1];
  const float* ob = (const float*)d_in[2];
  const float* mw = (const float*)d_in[3];
  const float* mb = (const float*)d_in[4];
  float* out  = (float*)d_out;
  float* offs = (float*)d_ws;                                        // 4.5 MB
  unsigned short* wt  = (unsigned short*)((char*)d_ws + 4718592);    // 144 KB
  unsigned short* xt  = (unsigned short*)((char*)d_ws + 4866048);    // 8 MB
  unsigned short* wot = (unsigned short*)((char*)d_ws + 13254656);   // 36 KB

  prep_w<<<360, 256, 0, stream>>>(mw, ow, wt, wot);
  x_to_nhwc<<<512, 256, 0, stream>>>(x, xt);
  offs_mfma<<<512, 256, 0, stream>>>(xt, wot, ob, offs);
  deform_mfma<<<1024, 256, 0, stream>>>(xt, offs, wt, mb, out);
}